// Round 5
// baseline (202.899 us; speedup 1.0000x reference)
//
#include <hip/hip_runtime.h>
#include <stdint.h>

// Flash attention fwd, B=16, L=2048, D=128, fp32 in/out.
// R12: 16-wave single-block occupancy. LDS-shrink occupancy push refuted
// (48K->2, 40K->2, 72K->1.4 blocks/CU); instead ONE 1024-thread block per
// CU (grid 256 = CU count) = 16 waves = 4/SIMD, double the latency hiding.
//  - in-block kv-split: waves 0-7 kv[0,32), 8-15 kv[32,64) per 64-tile;
//    per wave 32q x 32kv (same read:MFMA ratio, same ~84 VGPR as R7).
//  - K/V double-buffered, ONE barrier/tile (R8 loop, valid at fixed occ);
//    one global_load_lds per tensor per tile (1024 thr x 16B = 16 KB).
//  - P per wave 32 rows x 40 u16 (stride-80B, <=2-way conflicts, R10-proven).
//  - kv-halves merged via 2-round LDS epilogue (R10 pattern) -> partials
//    16.8 MB (was 24), combine sums 2, WS 33.8 MB.
// LDS: Kdbuf 32K | Vdbuf 32K | P 16x2560B = 40K -> 104 KB, 1 block/CU.

typedef short bf16x8 __attribute__((ext_vector_type(8)));
typedef float f32x4 __attribute__((ext_vector_type(4)));
typedef unsigned int u32;
typedef unsigned short u16;

#define L_SEQ  2048
#define D_HEAD 128
#define TSZ    8388608u                          // bytes per bf16 tensor
#define W_PART (2u * TSZ)                        // 256 x 64 KB partials
#define W_LSUM (W_PART + 256u * 65536u)
#define WS_NEED (W_LSUM + 256u * 256u * 4u)      // 33,816,576 B

__device__ __forceinline__ unsigned pk2(float lo, float hi) {
    union { float f; unsigned u; } a, b;
    a.f = lo; b.f = hi;
    return __builtin_amdgcn_perm(b.u + 0x8000u, a.u + 0x8000u, 0x07060302u);
}
__device__ __forceinline__ float ex2(float x) { return __builtin_amdgcn_exp2f(x); }
__device__ __forceinline__ float bflo(unsigned w) {
    union { unsigned u; float f; } v; v.u = w << 16; return v.f;
}
__device__ __forceinline__ float bfhi(unsigned w) {
    union { unsigned u; float f; } v; v.u = w & 0xffff0000u; return v.f;
}
__device__ __forceinline__ void gl_lds16(const u16* g, u16* l) {
    __builtin_amdgcn_global_load_lds(
        (const __attribute__((address_space(1))) u32*)g,
        (__attribute__((address_space(3))) u32*)l, 16, 0, 0);
}

// ---------------- pre-pass (unchanged, proven) -----------------------------
// wg 0..511:  K -> bf16 rows, granule swizzle gp_stored = gp_logical^(row&7)
// wg 512..1023: V -> V^T bf16 tiles [tile][d=128][8 gp swz][8 kv], vectorized
__global__ __launch_bounds__(256, 4)
void prepass(const float* __restrict__ K, const float* __restrict__ V,
             u16* __restrict__ kb, u16* __restrict__ vt) {
    const int id = blockIdx.x, t = threadIdx.x;
    if (id < 512) {
        const float* src = K + (size_t)id * 64 * 128;
        u16*        dst = kb + (size_t)id * 64 * 128;
        const int r = t >> 2;
        #pragma unroll
        for (int i = 0; i < 4; ++i) {
            int gp = (t & 3) * 4 + i;
            int gs = gp ^ (r & 7);
            const float* s = src + r * 128 + gs * 8;
            float4 x0 = *(const float4*)s, x1 = *(const float4*)(s + 4);
            uint4 w;
            w.x = pk2(x0.x, x0.y); w.y = pk2(x0.z, x0.w);
            w.z = pk2(x1.x, x1.y); w.w = pk2(x1.z, x1.w);
            *(uint4*)(dst + r * 128 + gp * 8) = w;
        }
    } else {
        // V^T: register 8x4 transpose -> LDS rows (b128) -> swizzled stores
        __shared__ __align__(16) u16 vl[128 * 72];
        const int bid = id - 512;
        const float* src = V + (size_t)bid * 64 * 128;
        const int vcc = t & 31, vgk = t >> 5;
        union { float4 v; float f[4]; } vr[8];
        const float* vp = src + (size_t)(vgk * 8) * 128 + vcc * 4;
        #pragma unroll
        for (int r = 0; r < 8; ++r) vr[r].v = *(const float4*)(vp + (size_t)r * 128);
        #pragma unroll
        for (int dd = 0; dd < 4; ++dd) {
            uint4 w;
            w.x = pk2(vr[0].f[dd], vr[1].f[dd]);
            w.y = pk2(vr[2].f[dd], vr[3].f[dd]);
            w.z = pk2(vr[4].f[dd], vr[5].f[dd]);
            w.w = pk2(vr[6].f[dd], vr[7].f[dd]);
            *(uint4*)(&vl[(vcc * 4 + dd) * 72 + vgk * 8]) = w;
        }
        __syncthreads();
        u16* dst = vt + (size_t)bid * 8192;
        #pragma unroll
        for (int i = 0; i < 4; ++i) {
            int flat = t + 256 * i;
            int d = flat >> 3, gp = flat & 7;
            uint4 w = *(const uint4*)(&vl[d * 72 + ((gp ^ (d & 7)) * 8)]);
            *(uint4*)(dst + (size_t)flat * 8) = w;
        }
    }
}

// ---------------- main kernel: 16 waves, in-block kv-split -----------------
// LDS: Kdbuf [2][16K] @0, Vdbuf [2][16K] @32768, P @65536 (16wv x 2560B)
__global__ __launch_bounds__(1024, 4)
void attn16(const float* __restrict__ Qg, const u16* __restrict__ kb,
            const u16* __restrict__ vt, u16* __restrict__ part,
            float* __restrict__ lsum) {
    __shared__ __align__(16) char smem[106496];
    const int tid = threadIdx.x;
    const int wv = tid >> 6, lane = tid & 63;
    const int c = lane & 15, qd = lane >> 4, cx = c & 7;
    const int wl = wv & 7, wh = wv >> 3;           // wl: q strip, wh: kv half
    const int bid = blockIdx.x;
    const int kvh = bid >> 7, p = bid & 127;       // kvh in {0,1}
    const int b = p >> 3, qblk = p & 7;            // qblk: 256 q rows
    const int nt = 16;                             // 64-kv tiles per block

    const float* Qp = Qg + (size_t)b * L_SEQ * D_HEAD;
    const u16*   Kp = kb + (size_t)b * L_SEQ * D_HEAD + (size_t)kvh * 16 * 8192;
    const u16*   Vp = vt + (size_t)b * 32 * 8192 + (size_t)kvh * 16 * 8192;
    u16* Pl = (u16*)(smem + 65536) + wv * 1280;    // 32 rows x 40 u16

    const int so = tid * 8;                        // DMA offset, u16 units

    auto stage = [&](int t, int buf) {
        u16* Kd = (u16*)smem + buf * 8192;
        u16* Vd = (u16*)(smem + 32768) + buf * 8192;
        gl_lds16(Kp + (size_t)t * 8192 + so, Kd + so);
        gl_lds16(Vp + (size_t)t * 8192 + so, Vd + so);
    };

    stage(0, 0);

    const float QS = 1.4426950408889634f / 11.313708498984761f; // log2e/sqrt(128)
    bf16x8 qf[2][4];
    #pragma unroll
    for (int s = 0; s < 2; ++s) {
        const float* qrow = Qp + (size_t)(qblk * 256 + wl * 32 + s * 16 + c) * 128 + qd * 8;
        #pragma unroll
        for (int kt = 0; kt < 4; ++kt) {
            float4 x0 = *(const float4*)(qrow + kt * 32);
            float4 x1 = *(const float4*)(qrow + kt * 32 + 4);
            union { unsigned u[4]; bf16x8 v; } tt;
            tt.u[0] = pk2(x0.x * QS, x0.y * QS);
            tt.u[1] = pk2(x0.z * QS, x0.w * QS);
            tt.u[2] = pk2(x1.x * QS, x1.y * QS);
            tt.u[3] = pk2(x1.z * QS, x1.w * QS);
            qf[s][kt] = tt.v;
        }
    }

    f32x4 acc[2][8];
    #pragma unroll
    for (int s = 0; s < 2; ++s)
        #pragma unroll
        for (int dt = 0; dt < 8; ++dt) acc[s][dt] = (f32x4){0.f, 0.f, 0.f, 0.f};
    float lrun[2] = {0.f, 0.f};

    __syncthreads();   // tile 0 staged (implicit vmcnt drain)

    #pragma unroll 2
    for (int it = 0; it < nt; ++it) {
        const int cur = it & 1;
        if (it + 1 < nt) stage(it + 1, cur ^ 1);   // full tile of hiding

        const u16* Kc = (const u16*)smem + cur * 8192;
        const u16* Vc = (const u16*)(smem + 32768) + cur * 8192;

        // ---- S^T(32kv-half x 32q) = K(half).Q^T
        f32x4 st[2][2];
        #pragma unroll
        for (int v = 0; v < 2; ++v) {
            st[v][0] = (f32x4){0.f, 0.f, 0.f, 0.f};
            st[v][1] = (f32x4){0.f, 0.f, 0.f, 0.f};
        }
        #pragma unroll
        for (int kt = 0; kt < 4; ++kt) {
            const int g = ((kt * 4 + qd) ^ cx) * 8;
            #pragma unroll
            for (int v = 0; v < 2; ++v) {
                bf16x8 a = *(const bf16x8*)(Kc + (wh * 32 + v * 16 + c) * 128 + g);
                st[v][0] = __builtin_amdgcn_mfma_f32_16x16x32_bf16(a, qf[0][kt], st[v][0], 0, 0, 0);
                st[v][1] = __builtin_amdgcn_mfma_f32_16x16x32_bf16(a, qf[1][kt], st[v][1], 0, 0, 0);
            }
        }

        // ---- sum-only softmax + per-wave P round-trip (stride-40 rows)
        bf16x8 pf[2];
        #pragma unroll
        for (int s = 0; s < 2; ++s) {
            float lsm = 0.f;
            #pragma unroll
            for (int v = 0; v < 2; ++v) {
                float p0 = ex2(st[v][s].x), p1 = ex2(st[v][s].y);
                float p2 = ex2(st[v][s].z), p3 = ex2(st[v][s].w);
                lsm += (p0 + p1) + (p2 + p3);
                uint2 w; w.x = pk2(p0, p1); w.y = pk2(p2, p3);
                *(uint2*)(Pl + (s * 16 + c) * 40 + (v * 4 + qd) * 4) = w;
            }
            lrun[s] += lsm;
            pf[s] = *(const bf16x8*)(Pl + (s * 16 + c) * 40 + qd * 8);
        }

        // ---- O^T(partial) += V^T(half).P^T
        #pragma unroll
        for (int dt = 0; dt < 8; ++dt) {
            bf16x8 av = *(const bf16x8*)(Vc + (dt * 16 + c) * 64 + ((wh * 4 + qd) ^ cx) * 8);
            acc[0][dt] = __builtin_amdgcn_mfma_f32_16x16x32_bf16(av, pf[0], acc[0][dt], 0, 0, 0);
            acc[1][dt] = __builtin_amdgcn_mfma_f32_16x16x32_bf16(av, pf[1], acc[1][dt], 0, 0, 0);
        }

        // single barrier per tile: drains next-tile DMA; frees current bufs
        if (it + 1 < nt) __syncthreads();
    }

    // ---- epilogue: qd-reduce l, merge kv-halves (2 rounds), store partials
    float ls[2];
    #pragma unroll
    for (int s = 0; s < 2; ++s) {
        float l = lrun[s];
        l += __shfl_xor(l, 16);
        l += __shfl_xor(l, 32);
        ls[s] = l;
    }
    float* lsh = (float*)(smem + 65536);           // reuse P region
    __syncthreads();                               // E0: loop LDS dead
    if (wh == 1) {
        if (qd == 0) {
            lsh[wl * 32 + c]      = ls[0];
            lsh[wl * 32 + 16 + c] = ls[1];
        }
        #pragma unroll
        for (int dt = 0; dt < 8; ++dt)
            *(f32x4*)(smem + (wl * 8 + dt) * 1024 + lane * 16) = acc[0][dt];
    }
    __syncthreads();                               // E1
    float lf0 = 0.f, lf1 = 0.f;
    if (wh == 0) {
        lf0 = ls[0] + lsh[wl * 32 + c];
        lf1 = ls[1] + lsh[wl * 32 + 16 + c];
        #pragma unroll
        for (int dt = 0; dt < 8; ++dt)
            acc[0][dt] += *(const f32x4*)(smem + (wl * 8 + dt) * 1024 + lane * 16);
    }
    __syncthreads();                               // E2: round-A reads done
    if (wh == 1) {
        #pragma unroll
        for (int dt = 0; dt < 8; ++dt)
            *(f32x4*)(smem + (wl * 8 + dt) * 1024 + lane * 16) = acc[1][dt];
    }
    __syncthreads();                               // E3
    if (wh == 0) {
        #pragma unroll
        for (int dt = 0; dt < 8; ++dt)
            acc[1][dt] += *(const f32x4*)(smem + (wl * 8 + dt) * 1024 + lane * 16);
        u16* pb = part + (size_t)bid * 32768 + wl * 4096;
        #pragma unroll
        for (int s = 0; s < 2; ++s)
            #pragma unroll
            for (int dt = 0; dt < 8; ++dt) {
                f32x4 o = acc[s][dt];
                uint2 w; w.x = pk2(o.x, o.y); w.y = pk2(o.z, o.w);
                *(uint2*)(pb + (((s * 8 + dt) * 64 + lane) << 2)) = w;
            }
        if (qd == 0) {
            lsum[bid * 256 + wl * 32 + c]      = lf0;
            lsum[bid * 256 + wl * 32 + 16 + c] = lf1;
        }
    }
}

// ---------------- combine: O = (O0+O1)/(l0+l1), transpose, store -----------
__global__ __launch_bounds__(256, 2)
void combine16(const u16* __restrict__ part, const float* __restrict__ lsum,
               float* __restrict__ Og) {
    __shared__ float inv[128];
    __shared__ __align__(16) float Ol[64 * 132];
    const int t = threadIdx.x, g = blockIdx.x;
    const int qb = g >> 1, half = g & 1;           // qb = b*8 + qblk
    const int b = qb >> 3, qblk = qb & 7;
    if (t < 128) {
        float l0 = lsum[(size_t)qb * 256 + half * 128 + t];
        float l1 = lsum[(size_t)(128 + qb) * 256 + half * 128 + t];
        inv[t] = 1.0f / (l0 + l1);
    }
    const uint2* S0 = (const uint2*)(part + (size_t)qb * 32768 + (size_t)half * 16384);
    const uint2* S1 = (const uint2*)(part + (size_t)(128 + qb) * 32768 + (size_t)half * 16384);
    __syncthreads();
    #pragma unroll
    for (int h2 = 0; h2 < 2; ++h2) {
        #pragma unroll
        for (int i = 0; i < 8; ++i) {
            int slot = i * 256 + t;
            int lc = slot >> 6, lane = slot & 63;
            int s = (lc >> 3) & 1, dt = lc & 7;
            int qd = lane >> 4, cc = lane & 15;
            int row = (lc >> 4) * 32 + s * 16 + cc;
            int d0 = dt * 16 + qd * 4;
            size_t idx = (size_t)(h2 * 2 + (lc >> 4)) * 1024 + (s * 8 + dt) * 64 + lane;
            uint2 w0 = S0[idx], w1 = S1[idx];
            float iv = inv[h2 * 64 + row];
            float4 o;
            o.x = (bflo(w0.x) + bflo(w1.x)) * iv;
            o.y = (bfhi(w0.x) + bfhi(w1.x)) * iv;
            o.z = (bflo(w0.y) + bflo(w1.y)) * iv;
            o.w = (bfhi(w0.y) + bfhi(w1.y)) * iv;
            *(float4*)(&Ol[row * 132 + d0]) = o;
        }
        __syncthreads();
        #pragma unroll
        for (int i = 0; i < 8; ++i) {
            int slot = i * 256 + t;
            int row = slot >> 5, c4 = slot & 31;
            float4 val = *(const float4*)(&Ol[row * 132 + c4 * 4]);
            size_t q = (size_t)b * L_SEQ + qblk * 256 + half * 128 + h2 * 64 + row;
            *(float4*)(Og + q * D_HEAD + c4 * 4) = val;
        }
        __syncthreads();
    }
}

extern "C" void kernel_launch(void* const* d_in, const int* in_sizes, int n_in,
                              void* d_out, int out_size, void* d_ws, size_t ws_size,
                              hipStream_t stream) {
    const float* q = (const float*)d_in[0];
    const float* k = (const float*)d_in[1];
    const float* v = (const float*)d_in[2];
    float* out = (float*)d_out;
    u16* kb = (u16*)d_ws;
    u16* vt = (u16*)((char*)d_ws + TSZ);
    u16* part = (u16*)((char*)d_ws + W_PART);
    float* ls = (float*)((char*)d_ws + W_LSUM);
    prepass<<<dim3(1024), dim3(256), 0, stream>>>(k, v, kb, vt);
    attn16<<<dim3(256), dim3(1024), 0, stream>>>(q, kb, vt, part, ls);
    combine16<<<dim3(256), dim3(256), 0, stream>>>(part, ls, out);
}

// Round 6
// 136.601 us; speedup vs baseline: 1.4853x; 1.4853x over previous
//
#include <hip/hip_runtime.h>
#include <stdint.h>

// Flash attention fwd, B=16, L=2048, D=128, fp32 in/out.
// R13: d-split waves to break the register-occupancy cap. R12 postmortem:
// occupancy has been VGPR-limited all along (84 arch + 64 AGPR acc = 148 ->
// 2 waves/SIMD hard cap). Here each wave computes QK^T for ONE kv-half of
// the tile, publishes P through LDS, and does PV for ONE d-half over all
// 64 kv -> acc[2][4] = 32 AGPR, total ~112 regs <= 128 -> 4 waves/SIMD.
//  - 512-thr blocks: 8 waves = 4 q-strips (32q) x 2 d-halves; block = 128 q.
//  - grid 512 = 16b x 16qblk x 2kvh = 2 blocks/CU -> 16 waves/CU (50%).
//  - LDS 48K: K 16K | V 16K | P 16K (4 strips x 32q x 64kv bf16, swizzled).
//  - single-buffered K/V, R7 DMA cadence; P-exchange barrier doubles as
//    staging barrier (still 2 barriers/tile).
//  - no epilogue merge: waves own disjoint d-halves; combine sums l over
//    2 kvh x 2 dh.
// prepass unchanged. WS: kb 8.4M | vt 8.4M | part 512x32K=16.8M | lsum 512K.

typedef short bf16x8 __attribute__((ext_vector_type(8)));
typedef float f32x4 __attribute__((ext_vector_type(4)));
typedef unsigned int u32;
typedef unsigned short u16;

#define L_SEQ  2048
#define D_HEAD 128
#define TSZ    8388608u                          // bytes per bf16 tensor
#define W_PART (2u * TSZ)                        // 512 x 32 KB partials
#define W_LSUM (W_PART + 512u * 32768u)
#define WS_NEED (W_LSUM + 512u * 256u * 4u)      // 34,078,720 B

__device__ __forceinline__ unsigned pk2(float lo, float hi) {
    union { float f; unsigned u; } a, b;
    a.f = lo; b.f = hi;
    return __builtin_amdgcn_perm(b.u + 0x8000u, a.u + 0x8000u, 0x07060302u);
}
__device__ __forceinline__ float ex2(float x) { return __builtin_amdgcn_exp2f(x); }
__device__ __forceinline__ float bflo(unsigned w) {
    union { unsigned u; float f; } v; v.u = w << 16; return v.f;
}
__device__ __forceinline__ float bfhi(unsigned w) {
    union { unsigned u; float f; } v; v.u = w & 0xffff0000u; return v.f;
}
__device__ __forceinline__ void gl_lds16(const u16* g, u16* l) {
    __builtin_amdgcn_global_load_lds(
        (const __attribute__((address_space(1))) u32*)g,
        (__attribute__((address_space(3))) u32*)l, 16, 0, 0);
}

// ---------------- pre-pass (unchanged, proven) -----------------------------
// wg 0..511:  K -> bf16 rows, granule swizzle gp_stored = gp_logical^(row&7)
// wg 512..1023: V -> V^T bf16 tiles [tile][d=128][8 gp swz][8 kv], vectorized
__global__ __launch_bounds__(256, 4)
void prepass(const float* __restrict__ K, const float* __restrict__ V,
             u16* __restrict__ kb, u16* __restrict__ vt) {
    const int id = blockIdx.x, t = threadIdx.x;
    if (id < 512) {
        const float* src = K + (size_t)id * 64 * 128;
        u16*        dst = kb + (size_t)id * 64 * 128;
        const int r = t >> 2;
        #pragma unroll
        for (int i = 0; i < 4; ++i) {
            int gp = (t & 3) * 4 + i;
            int gs = gp ^ (r & 7);
            const float* s = src + r * 128 + gs * 8;
            float4 x0 = *(const float4*)s, x1 = *(const float4*)(s + 4);
            uint4 w;
            w.x = pk2(x0.x, x0.y); w.y = pk2(x0.z, x0.w);
            w.z = pk2(x1.x, x1.y); w.w = pk2(x1.z, x1.w);
            *(uint4*)(dst + r * 128 + gp * 8) = w;
        }
    } else {
        // V^T: register 8x4 transpose -> LDS rows (b128) -> swizzled stores
        __shared__ __align__(16) u16 vl[128 * 72];
        const int bid = id - 512;
        const float* src = V + (size_t)bid * 64 * 128;
        const int vcc = t & 31, vgk = t >> 5;
        union { float4 v; float f[4]; } vr[8];
        const float* vp = src + (size_t)(vgk * 8) * 128 + vcc * 4;
        #pragma unroll
        for (int r = 0; r < 8; ++r) vr[r].v = *(const float4*)(vp + (size_t)r * 128);
        #pragma unroll
        for (int dd = 0; dd < 4; ++dd) {
            uint4 w;
            w.x = pk2(vr[0].f[dd], vr[1].f[dd]);
            w.y = pk2(vr[2].f[dd], vr[3].f[dd]);
            w.z = pk2(vr[4].f[dd], vr[5].f[dd]);
            w.w = pk2(vr[6].f[dd], vr[7].f[dd]);
            *(uint4*)(&vl[(vcc * 4 + dd) * 72 + vgk * 8]) = w;
        }
        __syncthreads();
        u16* dst = vt + (size_t)bid * 8192;
        #pragma unroll
        for (int i = 0; i < 4; ++i) {
            int flat = t + 256 * i;
            int d = flat >> 3, gp = flat & 7;
            uint4 w = *(const uint4*)(&vl[d * 72 + ((gp ^ (d & 7)) * 8)]);
            *(uint4*)(dst + (size_t)flat * 8) = w;
        }
    }
}

// ---------------- main kernel: d-split waves -------------------------------
// LDS: Kbuf 0..16K, Vbuf 16K..32K, P 32K..48K (4 strips x 32 x 64 u16 swz)
__global__ __launch_bounds__(512, 4)
void attnD(const float* __restrict__ Qg, const u16* __restrict__ kb,
           const u16* __restrict__ vt, u16* __restrict__ part,
           float* __restrict__ lsum) {
    __shared__ __align__(16) char smem[49152];
    const int tid = threadIdx.x;
    const int wv = tid >> 6, lane = tid & 63;
    const int c = lane & 15, qd = lane >> 4, cx = c & 7;
    const int qs = wv >> 1, dh = wv & 1;           // q-strip / d-half (kv-half)
    const int bid = blockIdx.x;
    const int kvh = bid >> 8, p = bid & 255;       // kvh in {0,1}
    const int b = p & 15, qblk = p >> 4;           // 128 q rows per block
    const int nt = 16;                             // 64-kv tiles per wg

    const float* Qp = Qg + (size_t)b * L_SEQ * D_HEAD;
    const u16*   Kp = kb + (size_t)b * L_SEQ * D_HEAD + (size_t)kvh * 16 * 8192;
    const u16*   Vp = vt + (size_t)b * 32 * 8192 + (size_t)kvh * 16 * 8192;
    u16* Kl = (u16*)smem;
    u16* Vl = (u16*)(smem + 16384);
    u16* Pq = (u16*)(smem + 32768) + qs * 2048;    // 32 rows x 64 u16, swizzled
    const int psw = cx << 1;                       // P granule swizzle constant
    const int so = tid * 8;                        // DMA offset, u16 units

    // stage tile 0 (512 thr x 16 B = 8 KB per call, 2 calls per tensor)
    gl_lds16(Kp + so, Kl + so);
    gl_lds16(Kp + so + 4096, Kl + so + 4096);
    gl_lds16(Vp + so, Vl + so);
    gl_lds16(Vp + so + 4096, Vl + so + 4096);

    const float QS = 1.4426950408889634f / 11.313708498984761f; // log2e/sqrt(128)
    bf16x8 qf[2][4];
    #pragma unroll
    for (int s = 0; s < 2; ++s) {
        const float* qrow = Qp + (size_t)(qblk * 128 + qs * 32 + s * 16 + c) * 128 + qd * 8;
        #pragma unroll
        for (int kt = 0; kt < 4; ++kt) {
            float4 x0 = *(const float4*)(qrow + kt * 32);
            float4 x1 = *(const float4*)(qrow + kt * 32 + 4);
            union { unsigned u[4]; bf16x8 v; } tt;
            tt.u[0] = pk2(x0.x * QS, x0.y * QS);
            tt.u[1] = pk2(x0.z * QS, x0.w * QS);
            tt.u[2] = pk2(x1.x * QS, x1.y * QS);
            tt.u[3] = pk2(x1.z * QS, x1.w * QS);
            qf[s][kt] = tt.v;
        }
    }

    f32x4 acc[2][4];                               // d-half only: 32 AGPR
    #pragma unroll
    for (int s = 0; s < 2; ++s)
        #pragma unroll
        for (int dt = 0; dt < 4; ++dt) acc[s][dt] = (f32x4){0.f, 0.f, 0.f, 0.f};
    float lrun[2] = {0.f, 0.f};

    __syncthreads();   // tile 0 staged (implicit vmcnt drain)

    for (int it = 0; it < nt; ++it) {
        // ---- S^T(my kv-half x 32q) = K(half).Q^T
        f32x4 st[2][2];
        #pragma unroll
        for (int v = 0; v < 2; ++v) {
            st[v][0] = (f32x4){0.f, 0.f, 0.f, 0.f};
            st[v][1] = (f32x4){0.f, 0.f, 0.f, 0.f};
        }
        #pragma unroll
        for (int kt = 0; kt < 4; ++kt) {
            const int g = ((kt * 4 + qd) ^ cx) * 8;
            #pragma unroll
            for (int v = 0; v < 2; ++v) {
                bf16x8 a = *(const bf16x8*)(Kl + (dh * 32 + v * 16 + c) * 128 + g);
                st[v][0] = __builtin_amdgcn_mfma_f32_16x16x32_bf16(a, qf[0][kt], st[v][0], 0, 0, 0);
                st[v][1] = __builtin_amdgcn_mfma_f32_16x16x32_bf16(a, qf[1][kt], st[v][1], 0, 0, 0);
            }
        }

        // ---- sum-only softmax; publish P granules for my kv-half
        #pragma unroll
        for (int s = 0; s < 2; ++s) {
            float lsm = 0.f;
            #pragma unroll
            for (int v = 0; v < 2; ++v) {
                float p0 = ex2(st[v][s].x), p1 = ex2(st[v][s].y);
                float p2 = ex2(st[v][s].z), p3 = ex2(st[v][s].w);
                lsm += (p0 + p1) + (p2 + p3);
                uint2 w; w.x = pk2(p0, p1); w.y = pk2(p2, p3);
                int gsw = (dh * 8 + v * 4 + qd) ^ psw;     // granule swizzle
                *(uint2*)(Pq + (s * 16 + c) * 64 + gsw * 4) = w;
            }
            lrun[s] += lsm;
        }
        __syncthreads();   // B1: P visible to partner wave; K reads done

        if (it + 1 < nt) {   // K(it+1) DMA: lands by B2's implicit drain
            const u16* kg = Kp + (size_t)(it + 1) * 8192 + so;
            gl_lds16(kg, Kl + so);
            gl_lds16(kg + 4096, Kl + so + 4096);
        }

        // ---- PV for my d-half over ALL 64 kv
        bf16x8 pf[2][2];
        #pragma unroll
        for (int h = 0; h < 2; ++h) {
            int gsw = (h * 8 + qd * 2) ^ psw;              // even: b128 contig
            #pragma unroll
            for (int s = 0; s < 2; ++s)
                pf[h][s] = *(const bf16x8*)(Pq + (s * 16 + c) * 64 + gsw * 4);
        }
        #pragma unroll
        for (int dt = 0; dt < 4; ++dt) {
            #pragma unroll
            for (int h = 0; h < 2; ++h) {
                bf16x8 av = *(const bf16x8*)(Vl + (dh * 64 + dt * 16 + c) * 64
                                                + ((h * 4 + qd) ^ cx) * 8);
                acc[0][dt] = __builtin_amdgcn_mfma_f32_16x16x32_bf16(av, pf[h][0], acc[0][dt], 0, 0, 0);
                acc[1][dt] = __builtin_amdgcn_mfma_f32_16x16x32_bf16(av, pf[h][1], acc[1][dt], 0, 0, 0);
            }
        }

        if (it + 1 < nt) {
            __syncthreads();   // B2: V+P reads done; K(it+1) drained
            const u16* vg = Vp + (size_t)(it + 1) * 8192 + so;
            gl_lds16(vg, Vl + so);
            gl_lds16(vg + 4096, Vl + so + 4096);
        }
    }

    // ---- epilogue: qd-reduce l, store bf16 O^T d-half partial + l
    float ls[2];
    #pragma unroll
    for (int s = 0; s < 2; ++s) {
        float l = lrun[s];
        l += __shfl_xor(l, 16);
        l += __shfl_xor(l, 32);
        ls[s] = l;
    }
    u16* pb = part + (size_t)bid * 16384;   // 32 KB per wg (u16 units)
    #pragma unroll
    for (int s = 0; s < 2; ++s)
        #pragma unroll
        for (int dt = 0; dt < 4; ++dt) {
            f32x4 o = acc[s][dt];
            uint2 w; w.x = pk2(o.x, o.y); w.y = pk2(o.z, o.w);
            *(uint2*)(pb + ((((((qs * 2 + dh) * 2 + s) * 4 + dt) * 64) + lane) << 2)) = w;
        }
    if (qd == 0) {
        lsum[(size_t)bid * 256 + dh * 128 + qs * 32 + c]      = ls[0];
        lsum[(size_t)bid * 256 + dh * 128 + qs * 32 + 16 + c] = ls[1];
    }
}

// ---------------- combine: O = (O0+O1)/l, transpose, store -----------------
__global__ __launch_bounds__(256, 2)
void combineD(const u16* __restrict__ part, const float* __restrict__ lsum,
              float* __restrict__ Og) {
    __shared__ float inv[128];
    __shared__ __align__(16) float Ol[64 * 132];
    const int t = threadIdx.x, p = blockIdx.x;     // p = b | qblk<<4 encoding
    const int b = p & 15, qblk = p >> 4;
    if (t < 128) {
        float l = 0.f;
        #pragma unroll
        for (int kvh = 0; kvh < 2; ++kvh)
            #pragma unroll
            for (int dh = 0; dh < 2; ++dh)
                l += lsum[(size_t)(kvh * 256 + p) * 256 + dh * 128 + t];
        inv[t] = 1.0f / l;
    }
    const uint2* S0 = (const uint2*)(part + (size_t)p * 16384);
    const uint2* S1 = (const uint2*)(part + (size_t)(256 + p) * 16384);
    __syncthreads();
    #pragma unroll
    for (int h2 = 0; h2 < 2; ++h2) {               // 64-row halves (qs pairs)
        #pragma unroll
        for (int i = 0; i < 8; ++i) {
            int slot = i * 256 + t;                // 0..2047
            int qs_l = slot >> 10;
            int rem  = slot & 1023;
            int dh = rem >> 9, s = (rem >> 8) & 1;
            int dt = (rem >> 6) & 3, lane = rem & 63;
            int qd = lane >> 4, cc = lane & 15;
            int qs = h2 * 2 + qs_l;
            int rowl = qs_l * 32 + s * 16 + cc;    // within 64-half
            int row  = h2 * 64 + rowl;             // 0..127 (inv index)
            int d0 = dh * 64 + dt * 16 + qd * 4;
            size_t idx = (size_t)((((qs * 2 + dh) * 2 + s) * 4 + dt) * 64 + lane);
            uint2 w0 = S0[idx], w1 = S1[idx];
            float iv = inv[row];
            float4 o;
            o.x = (bflo(w0.x) + bflo(w1.x)) * iv;
            o.y = (bfhi(w0.x) + bfhi(w1.x)) * iv;
            o.z = (bflo(w0.y) + bflo(w1.y)) * iv;
            o.w = (bfhi(w0.y) + bfhi(w1.y)) * iv;
            *(float4*)(&Ol[rowl * 132 + d0]) = o;
        }
        __syncthreads();
        #pragma unroll
        for (int i = 0; i < 8; ++i) {
            int slot = i * 256 + t;
            int row = slot >> 5, c4 = slot & 31;
            float4 val = *(const float4*)(&Ol[row * 132 + c4 * 4]);
            size_t q = (size_t)b * L_SEQ + qblk * 128 + h2 * 64 + row;
            *(float4*)(Og + q * D_HEAD + c4 * 4) = val;
        }
        __syncthreads();
    }
}

extern "C" void kernel_launch(void* const* d_in, const int* in_sizes, int n_in,
                              void* d_out, int out_size, void* d_ws, size_t ws_size,
                              hipStream_t stream) {
    const float* q = (const float*)d_in[0];
    const float* k = (const float*)d_in[1];
    const float* v = (const float*)d_in[2];
    float* out = (float*)d_out;
    u16* kb = (u16*)d_ws;
    u16* vt = (u16*)((char*)d_ws + TSZ);
    u16* part = (u16*)((char*)d_ws + W_PART);
    float* ls = (float*)((char*)d_ws + W_LSUM);
    prepass<<<dim3(1024), dim3(256), 0, stream>>>(k, v, kb, vt);
    attnD<<<dim3(512), dim3(512), 0, stream>>>(q, kb, vt, part, ls);
    combineD<<<dim3(256), dim3(256), 0, stream>>>(part, ls, out);
}

// Round 7
// 136.184 us; speedup vs baseline: 1.4899x; 1.0031x over previous
//
#include <hip/hip_runtime.h>
#include <stdint.h>

// Flash attention fwd, B=16, L=2048, D=128, fp32 in/out.
// R14: in-register P via 32x32 MFMA + cvt_pk_bf16 + permlane32_swap (T12).
// R7/R8/R13 showed dur invariant to occupancy (17/25/33% all ~50us) ->
// LDS-pipe bound (208 KB per 128q-tile). This removes the P round-trip
// (48 KB/tile) and its lgkm serialization entirely:
//  - QK^T: A=K from LDS, B=Q regs, mfma_32x32x16 -> S^T col=q, 16 f32/lane.
//  - softmax in-reg (sum-only exp2), then v_cvt_pk_bf16_f32 pairs +
//    v_permlane32_swap_b32 produce PV B-fragments in registers: lane needs
//    k=8*hi+{0..7}; holds rows 4*hi+{0..3} mod 8 -> one hi<->lo swap.
//  - PV: A=V^T from LDS, B=pf regs, acc 4 x f32x16 (64 regs, full d=128).
//  - LDS 32 KB (K 16 + V 16), single-buffered, R7 2-barrier DMA cadence.
//  - block 256 thr = 4 q-strips x 32q; grid 512 = 16b x 16qblk x 2kvh.
// prepass unchanged. combine re-indexed for 32x32 partial layout.
// WS: kb 8.4M | vt 8.4M | part 512x32K=16.8M | lsum 256K = 33.8 MB.

typedef short bf16x8 __attribute__((ext_vector_type(8)));
typedef float f32x4 __attribute__((ext_vector_type(4)));
typedef float f32x16 __attribute__((ext_vector_type(16)));
typedef unsigned int u32;
typedef unsigned short u16;

#define L_SEQ  2048
#define D_HEAD 128
#define TSZ    8388608u                          // bytes per bf16 tensor
#define W_PART (2u * TSZ)                        // 512 x 32 KB partials
#define W_LSUM (W_PART + 512u * 32768u)
#define WS_NEED (W_LSUM + 512u * 128u * 4u)

__device__ __forceinline__ unsigned pk2(float lo, float hi) {
    union { float f; unsigned u; } a, b;
    a.f = lo; b.f = hi;
    return __builtin_amdgcn_perm(b.u + 0x8000u, a.u + 0x8000u, 0x07060302u);
}
__device__ __forceinline__ float ex2(float x) { return __builtin_amdgcn_exp2f(x); }
__device__ __forceinline__ float bflo(unsigned w) {
    union { unsigned u; float f; } v; v.u = w << 16; return v.f;
}
__device__ __forceinline__ float bfhi(unsigned w) {
    union { unsigned u; float f; } v; v.u = w & 0xffff0000u; return v.f;
}
__device__ __forceinline__ u32 cvtpk(float lo, float hi) {
    u32 d;
    asm("v_cvt_pk_bf16_f32 %0, %1, %2" : "=v"(d) : "v"(lo), "v"(hi));
    return d;
}
__device__ __forceinline__ void plswap(u32& a, u32& b) {
    // a' = {a.lo_lanes, b.lo_lanes}; b' = {a.hi_lanes, b.hi_lanes}
    asm volatile("v_permlane32_swap_b32 %0, %1" : "+v"(a), "+v"(b));
}
__device__ __forceinline__ void gl_lds16(const u16* g, u16* l) {
    __builtin_amdgcn_global_load_lds(
        (const __attribute__((address_space(1))) u32*)g,
        (__attribute__((address_space(3))) u32*)l, 16, 0, 0);
}

// ---------------- pre-pass (unchanged, proven) -----------------------------
__global__ __launch_bounds__(256, 4)
void prepass(const float* __restrict__ K, const float* __restrict__ V,
             u16* __restrict__ kb, u16* __restrict__ vt) {
    const int id = blockIdx.x, t = threadIdx.x;
    if (id < 512) {
        const float* src = K + (size_t)id * 64 * 128;
        u16*        dst = kb + (size_t)id * 64 * 128;
        const int r = t >> 2;
        #pragma unroll
        for (int i = 0; i < 4; ++i) {
            int gp = (t & 3) * 4 + i;
            int gs = gp ^ (r & 7);
            const float* s = src + r * 128 + gs * 8;
            float4 x0 = *(const float4*)s, x1 = *(const float4*)(s + 4);
            uint4 w;
            w.x = pk2(x0.x, x0.y); w.y = pk2(x0.z, x0.w);
            w.z = pk2(x1.x, x1.y); w.w = pk2(x1.z, x1.w);
            *(uint4*)(dst + r * 128 + gp * 8) = w;
        }
    } else {
        __shared__ __align__(16) u16 vl[128 * 72];
        const int bid = id - 512;
        const float* src = V + (size_t)bid * 64 * 128;
        const int vcc = t & 31, vgk = t >> 5;
        union { float4 v; float f[4]; } vr[8];
        const float* vp = src + (size_t)(vgk * 8) * 128 + vcc * 4;
        #pragma unroll
        for (int r = 0; r < 8; ++r) vr[r].v = *(const float4*)(vp + (size_t)r * 128);
        #pragma unroll
        for (int dd = 0; dd < 4; ++dd) {
            uint4 w;
            w.x = pk2(vr[0].f[dd], vr[1].f[dd]);
            w.y = pk2(vr[2].f[dd], vr[3].f[dd]);
            w.z = pk2(vr[4].f[dd], vr[5].f[dd]);
            w.w = pk2(vr[6].f[dd], vr[7].f[dd]);
            *(uint4*)(&vl[(vcc * 4 + dd) * 72 + vgk * 8]) = w;
        }
        __syncthreads();
        u16* dst = vt + (size_t)bid * 8192;
        #pragma unroll
        for (int i = 0; i < 4; ++i) {
            int flat = t + 256 * i;
            int d = flat >> 3, gp = flat & 7;
            uint4 w = *(const uint4*)(&vl[d * 72 + ((gp ^ (d & 7)) * 8)]);
            *(uint4*)(dst + (size_t)flat * 8) = w;
        }
    }
}

// ---------------- main kernel: 32x32 MFMA, in-register P -------------------
// LDS: Kbuf 0..16K, Vbuf 16K..32K. No P buffer.
__global__ __launch_bounds__(256, 2)
void attnR(const float* __restrict__ Qg, const u16* __restrict__ kb,
           const u16* __restrict__ vt, u16* __restrict__ part,
           float* __restrict__ lsum) {
    __shared__ __align__(16) char smem[32768];
    const int tid = threadIdx.x;
    const int qs = tid >> 6, lane = tid & 63;
    const int q32 = lane & 31, hi = lane >> 5;
    const int bid = blockIdx.x;
    const int kvh = bid >> 8, p = bid & 255;       // kvh in {0,1}
    const int b = p & 15, qblk = p >> 4;           // 128 q rows per block
    const int nt = 16;

    const float* Qp = Qg + (size_t)b * L_SEQ * D_HEAD;
    const u16*   Kp = kb + (size_t)b * L_SEQ * D_HEAD + (size_t)kvh * 16 * 8192;
    const u16*   Vp = vt + (size_t)b * 32 * 8192 + (size_t)kvh * 16 * 8192;
    u16* Kl = (u16*)smem;
    u16* Vl = (u16*)(smem + 16384);
    const int so = qs * 2048 + lane * 8;           // DMA offset, u16 units

    #pragma unroll
    for (int i = 0; i < 4; ++i) {
        gl_lds16(Kp + so + i * 512, Kl + so + i * 512);
        gl_lds16(Vp + so + i * 512, Vl + so + i * 512);
    }

    // Q fragments: lane provides col=q32, k = step*16 + hi*8 + {0..7}
    const float QS = 1.4426950408889634f / 11.313708498984761f; // log2e/sqrt(128)
    bf16x8 qf[8];
    {
        const float* qrow = Qp + (size_t)(qblk * 128 + qs * 32 + q32) * 128 + hi * 8;
        #pragma unroll
        for (int s8 = 0; s8 < 8; ++s8) {
            float4 x0 = *(const float4*)(qrow + s8 * 16);
            float4 x1 = *(const float4*)(qrow + s8 * 16 + 4);
            union { u32 u[4]; bf16x8 v; } tt;
            tt.u[0] = pk2(x0.x * QS, x0.y * QS);
            tt.u[1] = pk2(x0.z * QS, x0.w * QS);
            tt.u[2] = pk2(x1.x * QS, x1.y * QS);
            tt.u[3] = pk2(x1.z * QS, x1.w * QS);
            qf[s8] = tt.v;
        }
    }

    f32x16 acc[4];
    #pragma unroll
    for (int dt = 0; dt < 4; ++dt)
        acc[dt] = (f32x16){0.f,0.f,0.f,0.f,0.f,0.f,0.f,0.f,
                           0.f,0.f,0.f,0.f,0.f,0.f,0.f,0.f};
    float lrun = 0.f;

    __syncthreads();   // tile 0 staged (implicit vmcnt drain)

    for (int it = 0; it < nt; ++it) {
        // ---- S^T(64kv x 32q) = K.Q^T, two 32x32 tiles
        f32x16 st0 = (f32x16){0.f,0.f,0.f,0.f,0.f,0.f,0.f,0.f,
                              0.f,0.f,0.f,0.f,0.f,0.f,0.f,0.f};
        f32x16 st1 = st0;
        const int lx = q32 & 7;                    // K row swizzle key
        #pragma unroll
        for (int s8 = 0; s8 < 8; ++s8) {
            const int gs = ((s8 * 2 + hi) ^ lx) * 8;
            bf16x8 a0 = *(const bf16x8*)(Kl + q32 * 128 + gs);
            bf16x8 a1 = *(const bf16x8*)(Kl + (32 + q32) * 128 + gs);
            st0 = __builtin_amdgcn_mfma_f32_32x32x16_bf16(a0, qf[s8], st0, 0, 0, 0);
            st1 = __builtin_amdgcn_mfma_f32_32x32x16_bf16(a1, qf[s8], st1, 0, 0, 0);
        }
        __syncthreads();   // B1: K-reads done (all waves); V(it) DMA drained

        if (it + 1 < nt) {
            const u16* kg = Kp + (size_t)(it + 1) * 8192 + so;
            #pragma unroll
            for (int i = 0; i < 4; ++i) gl_lds16(kg + i * 512, Kl + so + i * 512);
        }

        // ---- softmax (sum-only) + pack P into PV B-fragments, in registers
        bf16x8 pf[4];
        #pragma unroll
        for (int v = 0; v < 2; ++v) {
            float pp[16];
            #pragma unroll
            for (int e = 0; e < 16; ++e) {
                float sv = (v == 0) ? st0[e] : st1[e];
                pp[e] = ex2(sv);
                lrun += pp[e];
            }
            u32 wa0 = cvtpk(pp[0], pp[1]),  wb0 = cvtpk(pp[4], pp[5]);
            u32 wa1 = cvtpk(pp[2], pp[3]),  wb1 = cvtpk(pp[6], pp[7]);
            plswap(wa0, wb0); plswap(wa1, wb1);
            u32 wc0 = cvtpk(pp[8], pp[9]),  wd0 = cvtpk(pp[12], pp[13]);
            u32 wc1 = cvtpk(pp[10], pp[11]), wd1 = cvtpk(pp[14], pp[15]);
            plswap(wc0, wd0); plswap(wc1, wd1);
            union { u32 u[4]; bf16x8 x; } t0, t1;
            t0.u[0] = wa0; t0.u[1] = wa1; t0.u[2] = wb0; t0.u[3] = wb1;
            t1.u[0] = wc0; t1.u[1] = wc1; t1.u[2] = wd0; t1.u[3] = wd1;
            pf[v * 2]     = t0.x;                  // kv v*32 + [0,16)
            pf[v * 2 + 1] = t1.x;                  // kv v*32 + [16,32)
        }

        // ---- O^T += V^T.P^T  (full d=128, 4 d-tiles x 4 k-steps)
        #pragma unroll
        for (int dt = 0; dt < 4; ++dt) {
            const int R = dt * 32 + q32;
            const int rx = R & 7;
            #pragma unroll
            for (int ks = 0; ks < 4; ++ks) {
                bf16x8 av = *(const bf16x8*)(Vl + R * 64 + ((ks * 2 + hi) ^ rx) * 8);
                acc[dt] = __builtin_amdgcn_mfma_f32_32x32x16_bf16(av, pf[ks], acc[dt], 0, 0, 0);
            }
        }
        __syncthreads();   // B2: V-reads done; K(it+1) DMA drained

        if (it + 1 < nt) {
            const u16* vg = Vp + (size_t)(it + 1) * 8192 + so;
            #pragma unroll
            for (int i = 0; i < 4; ++i) gl_lds16(vg + i * 512, Vl + so + i * 512);
        }
    }

    // ---- epilogue: l = own + partner half; store bf16 O^T partial + l
    float l = lrun + __shfl_xor(lrun, 32);
    uint2* pw = (uint2*)(part + (size_t)bid * 16384);
    #pragma unroll
    for (int dt = 0; dt < 4; ++dt) {
        f32x16 o = acc[dt];
        #pragma unroll
        for (int jj = 0; jj < 4; ++jj) {
            uint2 w;
            w.x = pk2(o[jj * 4 + 0], o[jj * 4 + 1]);
            w.y = pk2(o[jj * 4 + 2], o[jj * 4 + 3]);
            pw[(((qs * 4 + dt) * 4 + jj) << 6) + lane] = w;
        }
    }
    if (lane < 32)
        lsum[(size_t)bid * 128 + qs * 32 + lane] = l;
}

// ---------------- combine: O = (O0+O1)/l, transpose, store -----------------
// partial word (qs,dt,jj,lane): q = qs*32+(lane&31),
// d = dt*32 + 4*(lane>>5) + 8*jj + {0..3} (x:0,1  y:2,3)
__global__ __launch_bounds__(256, 2)
void combineR(const u16* __restrict__ part, const float* __restrict__ lsum,
              float* __restrict__ Og) {
    __shared__ float inv[128];
    __shared__ __align__(16) float Ol[64 * 132];
    const int t = threadIdx.x, p = blockIdx.x;
    const int b = p & 15, qblk = p >> 4;
    if (t < 128) {
        float l = lsum[(size_t)p * 128 + t] + lsum[(size_t)(256 + p) * 128 + t];
        inv[t] = 1.0f / l;
    }
    const uint2* S0 = (const uint2*)(part + (size_t)p * 16384);
    const uint2* S1 = (const uint2*)(part + (size_t)(256 + p) * 16384);
    __syncthreads();
    #pragma unroll
    for (int h = 0; h < 2; ++h) {                  // q-strip pairs
        #pragma unroll
        for (int i = 0; i < 8; ++i) {
            int slot = i * 256 + t;                // 0..2047
            int qs_l = slot >> 10;
            int dt   = (slot >> 8) & 3;
            int jj   = (slot >> 6) & 3;
            int lane = slot & 63;
            int hi = lane >> 5, q32 = lane & 31;
            int qs = h * 2 + qs_l;
            int row_l = qs_l * 32 + q32;           // 0..63
            int d0 = dt * 32 + hi * 4 + jj * 8;
            size_t idx = (size_t)(((qs * 4 + dt) * 4 + jj) << 6) + lane;
            uint2 w0 = S0[idx], w1 = S1[idx];
            float iv = inv[h * 64 + row_l];
            float4 o;
            o.x = (bflo(w0.x) + bflo(w1.x)) * iv;
            o.y = (bfhi(w0.x) + bfhi(w1.x)) * iv;
            o.z = (bflo(w0.y) + bflo(w1.y)) * iv;
            o.w = (bfhi(w0.y) + bfhi(w1.y)) * iv;
            *(float4*)(&Ol[row_l * 132 + d0]) = o;
        }
        __syncthreads();
        #pragma unroll
        for (int i = 0; i < 8; ++i) {
            int slot = i * 256 + t;
            int row = slot >> 5, c4 = slot & 31;
            float4 val = *(const float4*)(&Ol[row * 132 + c4 * 4]);
            size_t q = (size_t)b * L_SEQ + qblk * 128 + h * 64 + row;
            *(float4*)(Og + q * D_HEAD + c4 * 4) = val;
        }
        __syncthreads();
    }
}

extern "C" void kernel_launch(void* const* d_in, const int* in_sizes, int n_in,
                              void* d_out, int out_size, void* d_ws, size_t ws_size,
                              hipStream_t stream) {
    const float* q = (const float*)d_in[0];
    const float* k = (const float*)d_in[1];
    const float* v = (const float*)d_in[2];
    float* out = (float*)d_out;
    u16* kb = (u16*)d_ws;
    u16* vt = (u16*)((char*)d_ws + TSZ);
    u16* part = (u16*)((char*)d_ws + W_PART);
    float* ls = (float*)((char*)d_ws + W_LSUM);
    prepass<<<dim3(1024), dim3(256), 0, stream>>>(k, v, kb, vt);
    attnR<<<dim3(512), dim3(256), 0, stream>>>(q, kb, vt, part, ls);
    combineR<<<dim3(256), dim3(256), 0, stream>>>(part, ls, out);
}

// Round 8
// 132.756 us; speedup vs baseline: 1.5284x; 1.0258x over previous
//
#include <hip/hip_runtime.h>
#include <stdint.h>

// Flash attention fwd, B=16, L=2048, D=128, fp32 in/out.
// R15: R14 (32x32 MFMA, in-register P via cvt_pk+permlane32_swap) with
// CONFLICT-FREE granule-major LDS layouts. R14 postmortem: 4.19M bank-
// conflict cycles (6.8us/CU) because the 32x32 A-read has 32 lanes on 32
// distinct 256B-strided rows -> 8 slots x 4 lanes = 4-way on every b128.
// Fix: store K as [g=0..15][row=0..63][8u16], V^T as [gv=0..7][d=0..127]
// [8u16]. A-fragment reads become lane->consecutive-16B (the measured
// 12-cyc coalesced regime), zero conflicts, zero swizzle math.
//  - prepass reindexed (K granule-major; V phase-B d-fast, stores coalesced)
//  - attnR loop/barriers/epilogue/combine identical to R14.
// WS: kb 8.4M | vt 8.4M | part 512x32K=16.8M | lsum 256K = 33.8 MB.

typedef short bf16x8 __attribute__((ext_vector_type(8)));
typedef float f32x4 __attribute__((ext_vector_type(4)));
typedef float f32x16 __attribute__((ext_vector_type(16)));
typedef unsigned int u32;
typedef unsigned short u16;

#define L_SEQ  2048
#define D_HEAD 128
#define TSZ    8388608u                          // bytes per bf16 tensor
#define W_PART (2u * TSZ)                        // 512 x 32 KB partials
#define W_LSUM (W_PART + 512u * 32768u)
#define WS_NEED (W_LSUM + 512u * 128u * 4u)

__device__ __forceinline__ unsigned pk2(float lo, float hi) {
    union { float f; unsigned u; } a, b;
    a.f = lo; b.f = hi;
    return __builtin_amdgcn_perm(b.u + 0x8000u, a.u + 0x8000u, 0x07060302u);
}
__device__ __forceinline__ float ex2(float x) { return __builtin_amdgcn_exp2f(x); }
__device__ __forceinline__ float bflo(unsigned w) {
    union { unsigned u; float f; } v; v.u = w << 16; return v.f;
}
__device__ __forceinline__ float bfhi(unsigned w) {
    union { unsigned u; float f; } v; v.u = w & 0xffff0000u; return v.f;
}
__device__ __forceinline__ u32 cvtpk(float lo, float hi) {
    u32 d;
    asm("v_cvt_pk_bf16_f32 %0, %1, %2" : "=v"(d) : "v"(lo), "v"(hi));
    return d;
}
__device__ __forceinline__ void plswap(u32& a, u32& b) {
    asm volatile("v_permlane32_swap_b32 %0, %1" : "+v"(a), "+v"(b));
}
__device__ __forceinline__ void gl_lds16(const u16* g, u16* l) {
    __builtin_amdgcn_global_load_lds(
        (const __attribute__((address_space(1))) u32*)g,
        (__attribute__((address_space(3))) u32*)l, 16, 0, 0);
}

// ---------------- pre-pass: granule-major outputs --------------------------
// wg 0..511:  K tile id -> kb[id][g=0..15][r=0..63][8] bf16
// wg 512..1023: V tile -> vt[id][gv=0..7][d=0..127][8 kv] bf16 (V^T)
__global__ __launch_bounds__(256, 4)
void prepass(const float* __restrict__ K, const float* __restrict__ V,
             u16* __restrict__ kb, u16* __restrict__ vt) {
    const int id = blockIdx.x, t = threadIdx.x;
    if (id < 512) {
        const float* src = K + (size_t)id * 64 * 128;
        u16*        dst = kb + (size_t)id * 64 * 128;
        const int r = t >> 2;
        #pragma unroll
        for (int i = 0; i < 4; ++i) {
            int gp = (t & 3) * 4 + i;              // logical granule 0..15
            const float* s = src + r * 128 + gp * 8;
            float4 x0 = *(const float4*)s, x1 = *(const float4*)(s + 4);
            uint4 w;
            w.x = pk2(x0.x, x0.y); w.y = pk2(x0.z, x0.w);
            w.z = pk2(x1.x, x1.y); w.w = pk2(x1.z, x1.w);
            *(uint4*)(dst + (gp * 64 + r) * 8) = w;   // granule-major
        }
    } else {
        // V^T: register 8x4 transpose -> vl rows (stride 72) -> [gv][d] store
        __shared__ __align__(16) u16 vl[128 * 72];
        const int bid = id - 512;
        const float* src = V + (size_t)bid * 64 * 128;
        const int vcc = t & 31, vgk = t >> 5;
        union { float4 v; float f[4]; } vr[8];
        const float* vp = src + (size_t)(vgk * 8) * 128 + vcc * 4;
        #pragma unroll
        for (int r = 0; r < 8; ++r) vr[r].v = *(const float4*)(vp + (size_t)r * 128);
        #pragma unroll
        for (int dd = 0; dd < 4; ++dd) {
            uint4 w;
            w.x = pk2(vr[0].f[dd], vr[1].f[dd]);
            w.y = pk2(vr[2].f[dd], vr[3].f[dd]);
            w.z = pk2(vr[4].f[dd], vr[5].f[dd]);
            w.w = pk2(vr[6].f[dd], vr[7].f[dd]);
            *(uint4*)(&vl[(vcc * 4 + dd) * 72 + vgk * 8]) = w;
        }
        __syncthreads();
        u16* dst = vt + (size_t)bid * 8192;
        #pragma unroll
        for (int i = 0; i < 4; ++i) {
            int c = i * 256 + t;                   // chunk = gv*128 + d
            int gv = c >> 7, d = c & 127;
            uint4 w = *(const uint4*)(&vl[d * 72 + gv * 8]);
            *(uint4*)(dst + (size_t)c * 8) = w;    // coalesced store
        }
    }
}

// ---------------- main kernel: 32x32 MFMA, in-register P -------------------
// LDS: Kbuf 0..16K ([g][row][8]), Vbuf 16K..32K ([gv][d][8]). No P buffer.
__global__ __launch_bounds__(256, 2)
void attnR(const float* __restrict__ Qg, const u16* __restrict__ kb,
           const u16* __restrict__ vt, u16* __restrict__ part,
           float* __restrict__ lsum) {
    __shared__ __align__(16) char smem[32768];
    const int tid = threadIdx.x;
    const int qs = tid >> 6, lane = tid & 63;
    const int q32 = lane & 31, hi = lane >> 5;
    const int bid = blockIdx.x;
    const int kvh = bid >> 8, p = bid & 255;       // kvh in {0,1}
    const int b = p & 15, qblk = p >> 4;           // 128 q rows per block
    const int nt = 16;

    const float* Qp = Qg + (size_t)b * L_SEQ * D_HEAD;
    const u16*   Kp = kb + (size_t)b * L_SEQ * D_HEAD + (size_t)kvh * 16 * 8192;
    const u16*   Vp = vt + (size_t)b * 32 * 8192 + (size_t)kvh * 16 * 8192;
    u16* Kl = (u16*)smem;
    u16* Vl = (u16*)(smem + 16384);
    const int so = qs * 2048 + lane * 8;           // DMA offset, u16 units

    #pragma unroll
    for (int i = 0; i < 4; ++i) {
        gl_lds16(Kp + so + i * 512, Kl + so + i * 512);
        gl_lds16(Vp + so + i * 512, Vl + so + i * 512);
    }

    // Q fragments: lane provides col=q32, k = s8*16 + hi*8 + {0..7}
    const float QS = 1.4426950408889634f / 11.313708498984761f; // log2e/sqrt(128)
    bf16x8 qf[8];
    {
        const float* qrow = Qp + (size_t)(qblk * 128 + qs * 32 + q32) * 128 + hi * 8;
        #pragma unroll
        for (int s8 = 0; s8 < 8; ++s8) {
            float4 x0 = *(const float4*)(qrow + s8 * 16);
            float4 x1 = *(const float4*)(qrow + s8 * 16 + 4);
            union { u32 u[4]; bf16x8 v; } tt;
            tt.u[0] = pk2(x0.x * QS, x0.y * QS);
            tt.u[1] = pk2(x0.z * QS, x0.w * QS);
            tt.u[2] = pk2(x1.x * QS, x1.y * QS);
            tt.u[3] = pk2(x1.z * QS, x1.w * QS);
            qf[s8] = tt.v;
        }
    }

    f32x16 acc[4];
    #pragma unroll
    for (int dt = 0; dt < 4; ++dt)
        acc[dt] = (f32x16){0.f,0.f,0.f,0.f,0.f,0.f,0.f,0.f,
                           0.f,0.f,0.f,0.f,0.f,0.f,0.f,0.f};
    float lrun = 0.f;

    __syncthreads();   // tile 0 staged (implicit vmcnt drain)

    for (int it = 0; it < nt; ++it) {
        // ---- S^T(64kv x 32q) = K.Q^T, two 32x32 tiles.
        // K read: granule g = s8*2+hi fixed per 32-lane group, row = q32
        // consecutive -> lane->consecutive 16B chunks, conflict-free.
        f32x16 st0 = (f32x16){0.f,0.f,0.f,0.f,0.f,0.f,0.f,0.f,
                              0.f,0.f,0.f,0.f,0.f,0.f,0.f,0.f};
        f32x16 st1 = st0;
        const u16* Kbase = Kl + hi * 512 + q32 * 8;
        #pragma unroll
        for (int s8 = 0; s8 < 8; ++s8) {
            bf16x8 a0 = *(const bf16x8*)(Kbase + s8 * 1024);
            bf16x8 a1 = *(const bf16x8*)(Kbase + s8 * 1024 + 256);
            st0 = __builtin_amdgcn_mfma_f32_32x32x16_bf16(a0, qf[s8], st0, 0, 0, 0);
            st1 = __builtin_amdgcn_mfma_f32_32x32x16_bf16(a1, qf[s8], st1, 0, 0, 0);
        }
        __syncthreads();   // B1: K-reads done (all waves); V(it) DMA drained

        if (it + 1 < nt) {
            const u16* kg = Kp + (size_t)(it + 1) * 8192 + so;
            #pragma unroll
            for (int i = 0; i < 4; ++i) gl_lds16(kg + i * 512, Kl + so + i * 512);
        }

        // ---- softmax (sum-only) + pack P into PV B-fragments, in registers
        bf16x8 pf[4];
        #pragma unroll
        for (int v = 0; v < 2; ++v) {
            float pp[16];
            #pragma unroll
            for (int e = 0; e < 16; ++e) {
                float sv = (v == 0) ? st0[e] : st1[e];
                pp[e] = ex2(sv);
                lrun += pp[e];
            }
            u32 wa0 = cvtpk(pp[0], pp[1]),  wb0 = cvtpk(pp[4], pp[5]);
            u32 wa1 = cvtpk(pp[2], pp[3]),  wb1 = cvtpk(pp[6], pp[7]);
            plswap(wa0, wb0); plswap(wa1, wb1);
            u32 wc0 = cvtpk(pp[8], pp[9]),  wd0 = cvtpk(pp[12], pp[13]);
            u32 wc1 = cvtpk(pp[10], pp[11]), wd1 = cvtpk(pp[14], pp[15]);
            plswap(wc0, wd0); plswap(wc1, wd1);
            union { u32 u[4]; bf16x8 x; } t0, t1;
            t0.u[0] = wa0; t0.u[1] = wa1; t0.u[2] = wb0; t0.u[3] = wb1;
            t1.u[0] = wc0; t1.u[1] = wc1; t1.u[2] = wd0; t1.u[3] = wd1;
            pf[v * 2]     = t0.x;                  // kv v*32 + [0,16)
            pf[v * 2 + 1] = t1.x;                  // kv v*32 + [16,32)
        }

        // ---- O^T += V^T.P^T  (full d=128, 4 d-tiles x 4 k-steps)
        // V read: gv = ks*2+hi fixed per group, d = dt*32+q32 consecutive
        // -> conflict-free.
        const u16* Vbase = Vl + hi * 1024 + q32 * 8;
        #pragma unroll
        for (int dt = 0; dt < 4; ++dt) {
            #pragma unroll
            for (int ks = 0; ks < 4; ++ks) {
                bf16x8 av = *(const bf16x8*)(Vbase + ks * 2048 + dt * 256);
                acc[dt] = __builtin_amdgcn_mfma_f32_32x32x16_bf16(av, pf[ks], acc[dt], 0, 0, 0);
            }
        }
        __syncthreads();   // B2: V-reads done; K(it+1) DMA drained

        if (it + 1 < nt) {
            const u16* vg = Vp + (size_t)(it + 1) * 8192 + so;
            #pragma unroll
            for (int i = 0; i < 4; ++i) gl_lds16(vg + i * 512, Vl + so + i * 512);
        }
    }

    // ---- epilogue: l = own + partner half; store bf16 O^T partial + l
    float l = lrun + __shfl_xor(lrun, 32);
    uint2* pw = (uint2*)(part + (size_t)bid * 16384);
    #pragma unroll
    for (int dt = 0; dt < 4; ++dt) {
        f32x16 o = acc[dt];
        #pragma unroll
        for (int jj = 0; jj < 4; ++jj) {
            uint2 w;
            w.x = pk2(o[jj * 4 + 0], o[jj * 4 + 1]);
            w.y = pk2(o[jj * 4 + 2], o[jj * 4 + 3]);
            pw[(((qs * 4 + dt) * 4 + jj) << 6) + lane] = w;
        }
    }
    if (lane < 32)
        lsum[(size_t)bid * 128 + qs * 32 + lane] = l;
}

// ---------------- combine: O = (O0+O1)/l, transpose, store -----------------
// partial word (qs,dt,jj,lane): q = qs*32+(lane&31),
// d = dt*32 + 4*(lane>>5) + 8*jj + {0..3} (x:0,1  y:2,3)
__global__ __launch_bounds__(256, 2)
void combineR(const u16* __restrict__ part, const float* __restrict__ lsum,
              float* __restrict__ Og) {
    __shared__ float inv[128];
    __shared__ __align__(16) float Ol[64 * 132];
    const int t = threadIdx.x, p = blockIdx.x;
    const int b = p & 15, qblk = p >> 4;
    if (t < 128) {
        float l = lsum[(size_t)p * 128 + t] + lsum[(size_t)(256 + p) * 128 + t];
        inv[t] = 1.0f / l;
    }
    const uint2* S0 = (const uint2*)(part + (size_t)p * 16384);
    const uint2* S1 = (const uint2*)(part + (size_t)(256 + p) * 16384);
    __syncthreads();
    #pragma unroll
    for (int h = 0; h < 2; ++h) {                  // q-strip pairs
        #pragma unroll
        for (int i = 0; i < 8; ++i) {
            int slot = i * 256 + t;                // 0..2047
            int qs_l = slot >> 10;
            int dt   = (slot >> 8) & 3;
            int jj   = (slot >> 6) & 3;
            int lane = slot & 63;
            int hi = lane >> 5, q32 = lane & 31;
            int qs = h * 2 + qs_l;
            int row_l = qs_l * 32 + q32;           // 0..63
            int d0 = dt * 32 + hi * 4 + jj * 8;
            size_t idx = (size_t)(((qs * 4 + dt) * 4 + jj) << 6) + lane;
            uint2 w0 = S0[idx], w1 = S1[idx];
            float iv = inv[h * 64 + row_l];
            float4 o;
            o.x = (bflo(w0.x) + bflo(w1.x)) * iv;
            o.y = (bfhi(w0.x) + bfhi(w1.x)) * iv;
            o.z = (bflo(w0.y) + bflo(w1.y)) * iv;
            o.w = (bfhi(w0.y) + bfhi(w1.y)) * iv;
            *(float4*)(&Ol[row_l * 132 + d0]) = o;
        }
        __syncthreads();
        #pragma unroll
        for (int i = 0; i < 8; ++i) {
            int slot = i * 256 + t;
            int row = slot >> 5, c4 = slot & 31;
            float4 val = *(const float4*)(&Ol[row * 132 + c4 * 4]);
            size_t q = (size_t)b * L_SEQ + qblk * 128 + h * 64 + row;
            *(float4*)(Og + q * D_HEAD + c4 * 4) = val;
        }
        __syncthreads();
    }
}

extern "C" void kernel_launch(void* const* d_in, const int* in_sizes, int n_in,
                              void* d_out, int out_size, void* d_ws, size_t ws_size,
                              hipStream_t stream) {
    const float* q = (const float*)d_in[0];
    const float* k = (const float*)d_in[1];
    const float* v = (const float*)d_in[2];
    float* out = (float*)d_out;
    u16* kb = (u16*)d_ws;
    u16* vt = (u16*)((char*)d_ws + TSZ);
    u16* part = (u16*)((char*)d_ws + W_PART);
    float* ls = (float*)((char*)d_ws + W_LSUM);
    prepass<<<dim3(1024), dim3(256), 0, stream>>>(k, v, kb, vt);
    attnR<<<dim3(512), dim3(256), 0, stream>>>(q, kb, vt, part, ls);
    combineR<<<dim3(256), dim3(256), 0, stream>>>(part, ls, out);
}